// Round 5
// baseline (24.779 us; speedup 1.0000x reference)
//
#include <hip/hip_runtime.h>

// Problem constants (from reference setup_inputs)
#define BB   64
#define NQ   900
#define NC   256
#define NT   128

#define RPW  4    // rows per wave (one per 16-lane group in the reduce)
#define RPB  16   // rows per piece (4 waves)
#define CPB  3    // pieces per block; 57 chunks = 19 * 3
#define NBX  19

typedef const __attribute__((address_space(1))) void gas_t;
typedef __attribute__((address_space(3))) void las_t;

// DPP butterfly add across a 16-lane group (VALU pipe, no LDS)
template<int CTRL>
__device__ __forceinline__ float dpp_add(float x) {
    int y = __builtin_amdgcn_update_dpp(0, __float_as_int(x), CTRL, 0xF, 0xF, true);
    return x + __int_as_float(y);
}

#define WAITVM(N) do { \
    asm volatile("s_waitcnt vmcnt(" #N ")" ::: "memory"); \
    __builtin_amdgcn_sched_barrier(0); } while (0)
#define WAITLGKM0 do { \
    asm volatile("s_waitcnt lgkmcnt(0)" ::: "memory"); \
    __builtin_amdgcn_sched_barrier(0); } while (0)

__global__ __launch_bounds__(256, 4) void matcher_kernel(
    const float* __restrict__ logits,   // [B, NQ, 256]
    const float* __restrict__ pboxes,   // [B, NQ, 4] cxcywh
    const int*   __restrict__ tlabels,  // [B, 128]
    const float* __restrict__ tboxes,   // [B, 128, 4] cxcywh
    float* __restrict__ out)            // [B, NQ, 128]
{
    constexpr float W_BBOX = 5.0f, W_GIOU = 2.0f, EPS = 1e-6f;

    // raw logits staging: [buf][wave][4 rows * 256] = 32 KB, per-wave private
    __shared__ __align__(16) float raw[2][4][RPW * NC];
    __shared__ float ssum[RPB];

    const int wave   = threadIdx.x >> 6;
    const int lane   = threadIdx.x & 63;
    const int g      = lane >> 4;
    const int j      = lane & 15;
    const int b      = blockIdx.y;
    const int chunk0 = blockIdx.x * CPB;
    const int wr0    = wave * RPW;

    // ---- this lane's two targets: load + derive ONCE per block ----
    const int t0 = lane * 2;
    const int2   lbl = *reinterpret_cast<const int2*>(tlabels + b * NT + t0);
    const float4 ta  = *reinterpret_cast<const float4*>(tboxes + ((size_t)b * NT + t0) * 4);
    const float4 tbv = *reinterpret_cast<const float4*>(tboxes + ((size_t)b * NT + t0 + 1) * 4);

    const float ax1 = ta.x - 0.5f * ta.z, ay1 = ta.y - 0.5f * ta.w;
    const float ax2 = ta.x + 0.5f * ta.z, ay2 = ta.y + 0.5f * ta.w;
    const float aarea = fmaxf(ax2 - ax1, 0.0f) * fmaxf(ay2 - ay1, 0.0f);
    const float bx1 = tbv.x - 0.5f * tbv.z, by1 = tbv.y - 0.5f * tbv.w;
    const float bx2 = tbv.x + 0.5f * tbv.z, by2 = tbv.y + 0.5f * tbv.w;
    const float barea = fmaxf(bx2 - bx1, 0.0f) * fmaxf(by2 - by1, 0.0f);

    // stage piece p's 4 rows of raw logits into LDS buffer `buf` (0 VGPR cost)
    auto stage = [&](int p, int buf) {
        const int q0 = (chunk0 + p) * RPB + wr0;
        #pragma unroll
        for (int k = 0; k < RPW; ++k) {
            int q = q0 + k; q = q < NQ - 1 ? q : NQ - 1;            // tail clamp
            const float* src = logits + ((size_t)b * NQ + q) * NC + lane * 4;
            __builtin_amdgcn_global_load_lds((gas_t*)src,
                                             (las_t*)&raw[buf][wave][k * NC],
                                             16, 0, 0);
        }
    };
    auto loadpb = [&](int p, float4* pbv) {
        const int q0 = (chunk0 + p) * RPB + wr0;
        #pragma unroll
        for (int r = 0; r < RPW; ++r) {
            int q = q0 + r; q = q < NQ - 1 ? q : NQ - 1;
            pbv[r] = *reinterpret_cast<const float4*>(pboxes + ((size_t)b * NQ + q) * 4);
        }
    };

    auto compute = [&](int p, int buf, const float4* pbv) {
        const int q0 = (chunk0 + p) * RPB + wr0;
        const float* R = &raw[buf][wave][0];

        // early gathers of raw logits at label positions (independent of reduce)
        float ga[RPW], gb[RPW];
        #pragma unroll
        for (int r = 0; r < RPW; ++r) {
            ga[r] = R[r * NC + lbl.x];
            gb[r] = R[r * NC + lbl.y];
        }

        // row-sum: lane (g,j) reads 16 raw of row g, exps in registers
        const float* rr = R + g * NC + j * 4;
        const float4 v0 = *reinterpret_cast<const float4*>(rr);
        const float4 v1 = *reinterpret_cast<const float4*>(rr + 64);
        const float4 v2 = *reinterpret_cast<const float4*>(rr + 128);
        const float4 v3 = *reinterpret_cast<const float4*>(rr + 192);

        float s = (((__expf(v0.x) + __expf(v0.y)) + (__expf(v0.z) + __expf(v0.w)))
                +  ((__expf(v1.x) + __expf(v1.y)) + (__expf(v1.z) + __expf(v1.w))))
                + (((__expf(v2.x) + __expf(v2.y)) + (__expf(v2.z) + __expf(v2.w)))
                +  ((__expf(v3.x) + __expf(v3.y)) + (__expf(v3.z) + __expf(v3.w))));
        s = dpp_add<0xB1>(s);   // quad_perm xor1
        s = dpp_add<0x4E>(s);   // quad_perm xor2
        s = dpp_add<0x141>(s);  // row_half_mirror (sum of 8)
        s = dpp_add<0x140>(s);  // row_mirror      (sum of 16)
        if (j == 0) ssum[wr0 + g] = s;

        const float4 sums = *reinterpret_cast<const float4*>(&ssum[wr0]);
        const float inv[RPW] = {
            __builtin_amdgcn_rcpf(sums.x), __builtin_amdgcn_rcpf(sums.y),
            __builtin_amdgcn_rcpf(sums.z), __builtin_amdgcn_rcpf(sums.w) };

        #pragma unroll
        for (int r = 0; r < RPW; ++r) {
            const float p0 = __expf(ga[r]) * inv[r];
            const float p1 = __expf(gb[r]) * inv[r];

            const float px1 = pbv[r].x - 0.5f * pbv[r].z, py1 = pbv[r].y - 0.5f * pbv[r].w;
            const float px2 = pbv[r].x + 0.5f * pbv[r].z, py2 = pbv[r].y + 0.5f * pbv[r].w;
            const float parea = fmaxf(px2 - px1, 0.0f) * fmaxf(py2 - py1, 0.0f);

            // target A
            const float l1a = fabsf(pbv[r].x - ta.x) + fabsf(pbv[r].y - ta.y)
                            + fabsf(pbv[r].z - ta.z) + fabsf(pbv[r].w - ta.w);
            const float ia  = fmaxf(fminf(px2, ax2) - fmaxf(px1, ax1), 0.0f)
                            * fmaxf(fminf(py2, ay2) - fmaxf(py1, ay1), 0.0f);
            const float ua  = parea + aarea - ia + EPS;
            const float ea  = fmaxf(fmaxf(px2, ax2) - fminf(px1, ax1), 0.0f)
                            * fmaxf(fmaxf(py2, ay2) - fminf(py1, ay1), 0.0f) + EPS;
            const float gioua = ia * __builtin_amdgcn_rcpf(ua)
                              - (ea - ua) * __builtin_amdgcn_rcpf(ea);
            const float c0 = -p0 + W_BBOX * l1a - W_GIOU * gioua;

            // target B
            const float l1b = fabsf(pbv[r].x - tbv.x) + fabsf(pbv[r].y - tbv.y)
                            + fabsf(pbv[r].z - tbv.z) + fabsf(pbv[r].w - tbv.w);
            const float ib  = fmaxf(fminf(px2, bx2) - fmaxf(px1, bx1), 0.0f)
                            * fmaxf(fminf(py2, by2) - fmaxf(py1, by1), 0.0f);
            const float ub  = parea + barea - ib + EPS;
            const float eb  = fmaxf(fmaxf(px2, bx2) - fminf(px1, bx1), 0.0f)
                            * fmaxf(fmaxf(py2, by2) - fminf(py1, by1), 0.0f) + EPS;
            const float gioub = ib * __builtin_amdgcn_rcpf(ub)
                              - (eb - ub) * __builtin_amdgcn_rcpf(eb);
            const float c1 = -p1 + W_BBOX * l1b - W_GIOU * gioub;

            if (q0 < NQ)   // wave-uniform tail guard
                *reinterpret_cast<float2*>(out + ((size_t)b * NQ + q0 + r) * NT + t0) =
                    make_float2(c0, c1);
        }
    };

    float4 pb0[RPW], pb1[RPW];

    // prologue: fill the pipeline two pieces deep (targets=3, stage0=4, pb0=4,
    // stage1=4, pb1=4 VMEM ops outstanding)
    stage(0, 0);
    loadpb(0, pb0);
    stage(1, 1);
    loadpb(1, pb1);

    WAITVM(8);            // drain targets + stage0 + pb0; stage1+pb1 in flight
    compute(0, 0, pb0);

    WAITLGKM0;            // buf0 ds_reads done before DMA overwrites buf0
    stage(2, 0);
    loadpb(2, pb0);

    WAITVM(8);            // drain stage1 + pb1; stage2 + pb2 in flight
    compute(1, 1, pb1);

    WAITVM(0);            // drain stage2 + pb2
    compute(2, 0, pb0);
}

extern "C" void kernel_launch(void* const* d_in, const int* in_sizes, int n_in,
                              void* d_out, int out_size, void* d_ws, size_t ws_size,
                              hipStream_t stream) {
    const float* logits  = (const float*)d_in[0];
    const float* pboxes  = (const float*)d_in[1];
    const int*   tlabels = (const int*)d_in[2];
    const float* tboxes  = (const float*)d_in[3];
    float* out = (float*)d_out;

    dim3 grid(NBX, BB);
    matcher_kernel<<<grid, 256, 0, stream>>>(logits, pboxes, tlabels, tboxes, out);
}

// Round 7
// 20.988 us; speedup vs baseline: 1.1807x; 1.1807x over previous
//
#include <hip/hip_runtime.h>

// Problem constants (from reference setup_inputs)
#define BB   64
#define NQ   900
#define NC   256
#define NT   128

#define RPW  4    // rows per wave: one per 16-lane group
#define RPB  16   // rows per block (4 waves)
#define NCHUNK 57 // ceil(900/16); chunk 56: only wave 0 valid

typedef float f32x2 __attribute__((ext_vector_type(2)));

// DPP butterfly add across a 16-lane group (VALU pipe, no LDS)
template<int CTRL>
__device__ __forceinline__ float dpp_add(float x) {
    int y = __builtin_amdgcn_update_dpp(0, __float_as_int(x), CTRL, 0xF, 0xF, true);
    return x + __int_as_float(y);
}

__device__ __forceinline__ float lane_bcast(float x, int l) {
    return __int_as_float(__builtin_amdgcn_readlane(__float_as_int(x), l));
}

__global__ __launch_bounds__(256) void matcher_kernel(
    const float* __restrict__ logits,   // [B, NQ, 256]
    const float* __restrict__ pboxes,   // [B, NQ, 4] cxcywh
    const int*   __restrict__ tlabels,  // [B, 128]
    const float* __restrict__ tboxes,   // [B, 128, 4] cxcywh
    float* __restrict__ out)            // [B, NQ, 128]
{
    constexpr float W_BBOX = 5.0f, W_GIOU = 2.0f, EPS = 1e-6f;

    __shared__ __align__(16) float raw[RPB][NC];   // RAW logits, 16 KB, per-wave regions

    const int wave = threadIdx.x >> 6;
    const int lane = threadIdx.x & 63;
    const int g    = lane >> 4;
    const int j    = lane & 15;
    const int b    = blockIdx.y;
    const int q0   = blockIdx.x * RPB + wave * RPW;
    if (q0 >= NQ) return;               // wave-uniform exit (chunk 56, waves 1-3)
    const int wr0  = wave * RPW;

    // ---- issue all global loads up front ----
    int qg = q0 + g; qg = qg < NQ - 1 ? qg : NQ - 1;   // tail clamp (load only)
    const float* lrow = logits + ((size_t)b * NQ + qg) * NC + j * 4;
    const float4 v0 = *reinterpret_cast<const float4*>(lrow);
    const float4 v1 = *reinterpret_cast<const float4*>(lrow + 64);
    const float4 v2 = *reinterpret_cast<const float4*>(lrow + 128);
    const float4 v3 = *reinterpret_cast<const float4*>(lrow + 192);

    float4 pb[RPW];
    #pragma unroll
    for (int r = 0; r < RPW; ++r)
        pb[r] = *reinterpret_cast<const float4*>(pboxes + ((size_t)b * NQ + q0 + r) * 4);

    const int t0 = lane * 2;
    const int2   lbl = *reinterpret_cast<const int2*>(tlabels + b * NT + t0);
    const float4 ta  = *reinterpret_cast<const float4*>(tboxes + ((size_t)b * NT + t0) * 4);
    const float4 tbv = *reinterpret_cast<const float4*>(tboxes + ((size_t)b * NT + t0 + 1) * 4);

    // ---- stash RAW logits to LDS immediately (no exp on the write path) ----
    float* srow = &raw[wr0 + g][j * 4];
    *reinterpret_cast<float4*>(srow)       = v0;
    *reinterpret_cast<float4*>(srow + 64)  = v1;
    *reinterpret_cast<float4*>(srow + 128) = v2;
    *reinterpret_cast<float4*>(srow + 192) = v3;

    // ---- label gathers of raw logits (independent of the reduce chain) ----
    float ga[RPW], gb[RPW];
    #pragma unroll
    for (int r = 0; r < RPW; ++r) {
        ga[r] = raw[wr0 + r][lbl.x];
        gb[r] = raw[wr0 + r][lbl.y];
    }

    // ---- exp in registers + tree + DPP butterfly (VALU pipe only) ----
    float s = (((__expf(v0.x) + __expf(v0.y)) + (__expf(v0.z) + __expf(v0.w)))
            +  ((__expf(v1.x) + __expf(v1.y)) + (__expf(v1.z) + __expf(v1.w))))
            + (((__expf(v2.x) + __expf(v2.y)) + (__expf(v2.z) + __expf(v2.w)))
            +  ((__expf(v3.x) + __expf(v3.y)) + (__expf(v3.z) + __expf(v3.w))));
    s = dpp_add<0xB1>(s);   // quad_perm xor1
    s = dpp_add<0x4E>(s);   // quad_perm xor2
    s = dpp_add<0x141>(s);  // row_half_mirror (sum of 8)
    s = dpp_add<0x140>(s);  // row_mirror      (sum of 16)

    // group sums -> SGPR broadcast (no LDS round-trip)
    const float inv[RPW] = {
        __builtin_amdgcn_rcpf(lane_bcast(s, 0)),
        __builtin_amdgcn_rcpf(lane_bcast(s, 16)),
        __builtin_amdgcn_rcpf(lane_bcast(s, 32)),
        __builtin_amdgcn_rcpf(lane_bcast(s, 48)) };

    // ---- per-lane target constants ----
    const float ax1 = ta.x - 0.5f * ta.z, ay1 = ta.y - 0.5f * ta.w;
    const float ax2 = ta.x + 0.5f * ta.z, ay2 = ta.y + 0.5f * ta.w;
    const float aarea = fmaxf(ax2 - ax1, 0.0f) * fmaxf(ay2 - ay1, 0.0f);
    const float bx1 = tbv.x - 0.5f * tbv.z, by1 = tbv.y - 0.5f * tbv.w;
    const float bx2 = tbv.x + 0.5f * tbv.z, by2 = tbv.y + 0.5f * tbv.w;
    const float barea = fmaxf(bx2 - bx1, 0.0f) * fmaxf(by2 - by1, 0.0f);

    // ---- per row: prob at gather time, box costs, NT float2 store ----
    #pragma unroll
    for (int r = 0; r < RPW; ++r) {
        const float p0 = __expf(ga[r]) * inv[r];
        const float p1 = __expf(gb[r]) * inv[r];

        const float px1 = pb[r].x - 0.5f * pb[r].z, py1 = pb[r].y - 0.5f * pb[r].w;
        const float px2 = pb[r].x + 0.5f * pb[r].z, py2 = pb[r].y + 0.5f * pb[r].w;
        const float parea = fmaxf(px2 - px1, 0.0f) * fmaxf(py2 - py1, 0.0f);

        // target A
        const float l1a = fabsf(pb[r].x - ta.x) + fabsf(pb[r].y - ta.y)
                        + fabsf(pb[r].z - ta.z) + fabsf(pb[r].w - ta.w);
        const float ia  = fmaxf(fminf(px2, ax2) - fmaxf(px1, ax1), 0.0f)
                        * fmaxf(fminf(py2, ay2) - fmaxf(py1, ay1), 0.0f);
        const float ua  = parea + aarea - ia + EPS;
        const float ea  = fmaxf(fmaxf(px2, ax2) - fminf(px1, ax1), 0.0f)
                        * fmaxf(fmaxf(py2, ay2) - fminf(py1, ay1), 0.0f) + EPS;
        const float gioua = ia * __builtin_amdgcn_rcpf(ua)
                          - (ea - ua) * __builtin_amdgcn_rcpf(ea);
        const float c0 = -p0 + W_BBOX * l1a - W_GIOU * gioua;

        // target B
        const float l1b = fabsf(pb[r].x - tbv.x) + fabsf(pb[r].y - tbv.y)
                        + fabsf(pb[r].z - tbv.z) + fabsf(pb[r].w - tbv.w);
        const float ib  = fmaxf(fminf(px2, bx2) - fmaxf(px1, bx1), 0.0f)
                        * fmaxf(fminf(py2, by2) - fmaxf(py1, by1), 0.0f);
        const float ub  = parea + barea - ib + EPS;
        const float eb  = fmaxf(fmaxf(px2, bx2) - fminf(px1, bx1), 0.0f)
                        * fmaxf(fmaxf(py2, by2) - fminf(py1, by1), 0.0f) + EPS;
        const float gioub = ib * __builtin_amdgcn_rcpf(ub)
                          - (eb - ub) * __builtin_amdgcn_rcpf(eb);
        const float c1 = -p1 + W_BBOX * l1b - W_GIOU * gioub;

        f32x2 cc; cc.x = c0; cc.y = c1;
        __builtin_nontemporal_store(cc,
            reinterpret_cast<f32x2*>(out + ((size_t)b * NQ + q0 + r) * NT + t0));
    }
}

extern "C" void kernel_launch(void* const* d_in, const int* in_sizes, int n_in,
                              void* d_out, int out_size, void* d_ws, size_t ws_size,
                              hipStream_t stream) {
    const float* logits  = (const float*)d_in[0];
    const float* pboxes  = (const float*)d_in[1];
    const int*   tlabels = (const int*)d_in[2];
    const float* tboxes  = (const float*)d_in[3];
    float* out = (float*)d_out;

    dim3 grid(NCHUNK, BB);
    matcher_kernel<<<grid, 256, 0, stream>>>(logits, pboxes, tlabels, tboxes, out);
}

// Round 8
// 20.902 us; speedup vs baseline: 1.1855x; 1.0041x over previous
//
#include <hip/hip_runtime.h>

// Problem constants (from reference setup_inputs)
#define BB   64
#define NQ   900
#define NC   256
#define NT   128

#define RPW  4    // rows per wave: one per 16-lane group
#define RPB  16   // rows per block (4 waves)
#define NCHUNK 57 // ceil(900/16); chunk 56: only wave 0 valid

typedef float f32x2 __attribute__((ext_vector_type(2)));

// DPP butterfly add across a 16-lane group (VALU pipe, no LDS)
template<int CTRL>
__device__ __forceinline__ float dpp_add(float x) {
    int y = __builtin_amdgcn_update_dpp(0, __float_as_int(x), CTRL, 0xF, 0xF, true);
    return x + __int_as_float(y);
}

__device__ __forceinline__ float lane_bcast(float x, int l) {
    return __int_as_float(__builtin_amdgcn_readlane(__float_as_int(x), l));
}

// __launch_bounds__(256, 4): 4 waves/EU min -> VGPR capped at 128 ->
// guarantees 16 waves/CU. A/B probe vs R7 (identical code otherwise).
__global__ __launch_bounds__(256, 4) void matcher_kernel(
    const float* __restrict__ logits,   // [B, NQ, 256]
    const float* __restrict__ pboxes,   // [B, NQ, 4] cxcywh
    const int*   __restrict__ tlabels,  // [B, 128]
    const float* __restrict__ tboxes,   // [B, 128, 4] cxcywh
    float* __restrict__ out)            // [B, NQ, 128]
{
    constexpr float W_BBOX = 5.0f, W_GIOU = 2.0f, EPS = 1e-6f;

    __shared__ __align__(16) float raw[RPB][NC];   // RAW logits, 16 KB, per-wave regions

    const int wave = threadIdx.x >> 6;
    const int lane = threadIdx.x & 63;
    const int g    = lane >> 4;
    const int j    = lane & 15;
    const int b    = blockIdx.y;
    const int q0   = blockIdx.x * RPB + wave * RPW;
    if (q0 >= NQ) return;               // wave-uniform exit (chunk 56, waves 1-3)
    const int wr0  = wave * RPW;

    // ---- issue all global loads up front ----
    int qg = q0 + g; qg = qg < NQ - 1 ? qg : NQ - 1;   // tail clamp (load only)
    const float* lrow = logits + ((size_t)b * NQ + qg) * NC + j * 4;
    const float4 v0 = *reinterpret_cast<const float4*>(lrow);
    const float4 v1 = *reinterpret_cast<const float4*>(lrow + 64);
    const float4 v2 = *reinterpret_cast<const float4*>(lrow + 128);
    const float4 v3 = *reinterpret_cast<const float4*>(lrow + 192);

    float4 pb[RPW];
    #pragma unroll
    for (int r = 0; r < RPW; ++r)
        pb[r] = *reinterpret_cast<const float4*>(pboxes + ((size_t)b * NQ + q0 + r) * 4);

    const int t0 = lane * 2;
    const int2   lbl = *reinterpret_cast<const int2*>(tlabels + b * NT + t0);
    const float4 ta  = *reinterpret_cast<const float4*>(tboxes + ((size_t)b * NT + t0) * 4);
    const float4 tbv = *reinterpret_cast<const float4*>(tboxes + ((size_t)b * NT + t0 + 1) * 4);

    // ---- stash RAW logits to LDS immediately (no exp on the write path) ----
    float* srow = &raw[wr0 + g][j * 4];
    *reinterpret_cast<float4*>(srow)       = v0;
    *reinterpret_cast<float4*>(srow + 64)  = v1;
    *reinterpret_cast<float4*>(srow + 128) = v2;
    *reinterpret_cast<float4*>(srow + 192) = v3;

    // ---- label gathers of raw logits (independent of the reduce chain) ----
    float ga[RPW], gb[RPW];
    #pragma unroll
    for (int r = 0; r < RPW; ++r) {
        ga[r] = raw[wr0 + r][lbl.x];
        gb[r] = raw[wr0 + r][lbl.y];
    }

    // ---- exp in registers + tree + DPP butterfly (VALU pipe only) ----
    float s = (((__expf(v0.x) + __expf(v0.y)) + (__expf(v0.z) + __expf(v0.w)))
            +  ((__expf(v1.x) + __expf(v1.y)) + (__expf(v1.z) + __expf(v1.w))))
            + (((__expf(v2.x) + __expf(v2.y)) + (__expf(v2.z) + __expf(v2.w)))
            +  ((__expf(v3.x) + __expf(v3.y)) + (__expf(v3.z) + __expf(v3.w))));
    s = dpp_add<0xB1>(s);   // quad_perm xor1
    s = dpp_add<0x4E>(s);   // quad_perm xor2
    s = dpp_add<0x141>(s);  // row_half_mirror (sum of 8)
    s = dpp_add<0x140>(s);  // row_mirror      (sum of 16)

    // group sums -> SGPR broadcast (no LDS round-trip)
    const float inv[RPW] = {
        __builtin_amdgcn_rcpf(lane_bcast(s, 0)),
        __builtin_amdgcn_rcpf(lane_bcast(s, 16)),
        __builtin_amdgcn_rcpf(lane_bcast(s, 32)),
        __builtin_amdgcn_rcpf(lane_bcast(s, 48)) };

    // ---- per-lane target constants ----
    const float ax1 = ta.x - 0.5f * ta.z, ay1 = ta.y - 0.5f * ta.w;
    const float ax2 = ta.x + 0.5f * ta.z, ay2 = ta.y + 0.5f * ta.w;
    const float aarea = fmaxf(ax2 - ax1, 0.0f) * fmaxf(ay2 - ay1, 0.0f);
    const float bx1 = tbv.x - 0.5f * tbv.z, by1 = tbv.y - 0.5f * tbv.w;
    const float bx2 = tbv.x + 0.5f * tbv.z, by2 = tbv.y + 0.5f * tbv.w;
    const float barea = fmaxf(bx2 - bx1, 0.0f) * fmaxf(by2 - by1, 0.0f);

    // ---- per row: prob at gather time, box costs, NT float2 store ----
    #pragma unroll
    for (int r = 0; r < RPW; ++r) {
        const float p0 = __expf(ga[r]) * inv[r];
        const float p1 = __expf(gb[r]) * inv[r];

        const float px1 = pb[r].x - 0.5f * pb[r].z, py1 = pb[r].y - 0.5f * pb[r].w;
        const float px2 = pb[r].x + 0.5f * pb[r].z, py2 = pb[r].y + 0.5f * pb[r].w;
        const float parea = fmaxf(px2 - px1, 0.0f) * fmaxf(py2 - py1, 0.0f);

        // target A
        const float l1a = fabsf(pb[r].x - ta.x) + fabsf(pb[r].y - ta.y)
                        + fabsf(pb[r].z - ta.z) + fabsf(pb[r].w - ta.w);
        const float ia  = fmaxf(fminf(px2, ax2) - fmaxf(px1, ax1), 0.0f)
                        * fmaxf(fminf(py2, ay2) - fmaxf(py1, ay1), 0.0f);
        const float ua  = parea + aarea - ia + EPS;
        const float ea  = fmaxf(fmaxf(px2, ax2) - fminf(px1, ax1), 0.0f)
                        * fmaxf(fmaxf(py2, ay2) - fminf(py1, ay1), 0.0f) + EPS;
        const float gioua = ia * __builtin_amdgcn_rcpf(ua)
                          - (ea - ua) * __builtin_amdgcn_rcpf(ea);
        const float c0 = -p0 + W_BBOX * l1a - W_GIOU * gioua;

        // target B
        const float l1b = fabsf(pb[r].x - tbv.x) + fabsf(pb[r].y - tbv.y)
                        + fabsf(pb[r].z - tbv.z) + fabsf(pb[r].w - tbv.w);
        const float ib  = fmaxf(fminf(px2, bx2) - fmaxf(px1, bx1), 0.0f)
                        * fmaxf(fminf(py2, by2) - fmaxf(py1, by1), 0.0f);
        const float ub  = parea + barea - ib + EPS;
        const float eb  = fmaxf(fmaxf(px2, bx2) - fminf(px1, bx1), 0.0f)
                        * fmaxf(fmaxf(py2, by2) - fminf(py1, by1), 0.0f) + EPS;
        const float gioub = ib * __builtin_amdgcn_rcpf(ub)
                          - (eb - ub) * __builtin_amdgcn_rcpf(eb);
        const float c1 = -p1 + W_BBOX * l1b - W_GIOU * gioub;

        f32x2 cc; cc.x = c0; cc.y = c1;
        __builtin_nontemporal_store(cc,
            reinterpret_cast<f32x2*>(out + ((size_t)b * NQ + q0 + r) * NT + t0));
    }
}

extern "C" void kernel_launch(void* const* d_in, const int* in_sizes, int n_in,
                              void* d_out, int out_size, void* d_ws, size_t ws_size,
                              hipStream_t stream) {
    const float* logits  = (const float*)d_in[0];
    const float* pboxes  = (const float*)d_in[1];
    const int*   tlabels = (const int*)d_in[2];
    const float* tboxes  = (const float*)d_in[3];
    float* out = (float*)d_out;

    dim3 grid(NCHUNK, BB);
    matcher_kernel<<<grid, 256, 0, stream>>>(logits, pboxes, tlabels, tboxes, out);
}